// Round 10
// baseline (1213.518 us; speedup 1.0000x reference)
//
#include <hip/hip_runtime.h>
#include <math.h>

#define NCH     129
#define NT      250
#define DINNER  256
#define DSTATE  16
#define NHEADS  4
#define DPROJ   548   // z(256) + xh(256) + B(16) + C(16) + dt(4)
#define TC      16    // timesteps per chunk per batch; 250 = 15*16 + 10
#define NMT     18    // M tiles of 32 (576 >= 548)
#define NKS     8     // K steps of 16 (c=0..127); c=128 via VALU
#define ZRS     34    // zxlo ushort col stride (32 cols + 2 pad)
#define ZRF     33    // zxf float col stride

typedef __attribute__((ext_vector_type(8)))  short short8;
typedef __attribute__((ext_vector_type(16))) float f32x16;

template<int N> struct IC { static constexpr int value = N; };

__device__ __forceinline__ float silu_f(float x) { return x / (1.f + __expf(-x)); }

template<int CTRL>
__device__ __forceinline__ float dstep(float v) {
    int t = __builtin_amdgcn_update_dpp(0, __float_as_int(v), CTRL, 0xF, 0xF, true);
    return v + __int_as_float(t);
}
__device__ __forceinline__ float wave_sum63(float v) {
    v = dstep<0xB1>(v);  v = dstep<0x4E>(v);  v = dstep<0x141>(v);
    v = dstep<0x140>(v); v = dstep<0x142>(v); v = dstep<0x143>(v);
    return v;   // lane 63 = total
}
__device__ __forceinline__ float rdlane(float v, int l) {
    return __uint_as_float(__builtin_amdgcn_readlane(__float_as_uint(v), l));
}
__device__ __forceinline__ unsigned short f2bf(float f) {   // RNE
    unsigned u = __float_as_uint(f);
    u += 0x7FFF + ((u >> 16) & 1);
    return (unsigned short)(u >> 16);
}
__device__ __forceinline__ float bf2f(unsigned short h) {
    return __uint_as_float(((unsigned)h) << 16);
}

// ---------- prep: A-frags (LDS-staged GEMM), bias2/w128, vv ----------
__global__ __launch_bounds__(256) void k_prep(
    const float* __restrict__ in_proj_w,  // [548,128]
    const float* __restrict__ mixer_w,    // [128,129]
    const float* __restrict__ mixer_b,    // [128]
    const float* __restrict__ head_w,     // [1,128]
    const float* __restrict__ out_proj_w, // [128,256]
    unsigned short* __restrict__ ahi,
    unsigned short* __restrict__ alo,
    float* __restrict__ bias2,
    float* __restrict__ w128,
    float* __restrict__ vvp)
{
    int blk = blockIdx.x;
    int t = threadIdx.x;
    if (blk < NMT * NKS) {
        __shared__ float inp[32][129];
        __shared__ float mw[128][17];
        int mt = blk >> 3, ks = blk & 7;
        int m0 = mt * 32;
        for (int u = t; u < 32 * 128; u += 256) {
            int r = u >> 7, d = u & 127;
            inp[r][d] = (m0 + r < DPROJ) ? in_proj_w[(m0 + r) * 128 + d] : 0.f;
        }
        for (int u = t; u < 128 * 16; u += 256) {
            int d = u >> 4, kk = u & 15;
            mw[d][kk] = mixer_w[d * NCH + ks * 16 + kk];
        }
        __syncthreads();
        int lane = t & 63, sub = t >> 6;
        int mr = lane & 31;
        int kb = (lane >> 5) * 8;
#pragma unroll
        for (int ii = 0; ii < 2; ++ii) {
            int i = sub * 2 + ii;        // 0..7
            int kk = kb & 8 ? kb - 8 + i : i;   // kk = local col 0..15
            kk = (kb ? 8 : 0) + i;
            float acc = 0.f;
            for (int d = 0; d < 128; ++d)
                acc = fmaf(inp[mr][d], mw[d][kk], acc);
            unsigned short hb = f2bf(acc);
            size_t o = (((size_t)(mt * NKS + ks)) * 64 + lane) * 8 + i;
            ahi[o] = hb;
            alo[o] = f2bf(acc - bf2f(hb));
        }
    } else if (blk == NMT * NKS) {
#pragma unroll
        for (int r = 0; r < 3; ++r) {
            int j = (r == 0) ? t : (r == 1) ? t + 256 : 512 + t;
            if (r == 2 && t >= 36) break;
            float ab = 0.f, aw = 0.f;
            for (int d = 0; d < 128; ++d) {
                float w = in_proj_w[j * 128 + d];
                ab += w * mixer_b[d];
                aw += w * mixer_w[d * NCH + 128];
            }
            bias2[j] = ab;
            w128[j]  = aw;
        }
    } else {
        float acc = 0.f;
        for (int d = 0; d < 128; ++d)
            acc += head_w[d] * out_proj_w[d * DINNER + t];
        vvp[t] = acc;
    }
}

// ---------- fused, wave-specialized: 2 batches/block, 512 thr ----------
// waves 0-3 "compute": channels (wq*64+lane) for both batches: conv+scan+reduce.
// waves 4-7 "mfma": GEMM chunk s+1 (dbuf zx) + stage x chunk s+2.
__global__ __launch_bounds__(512, 1) void k_fused(
    const float* __restrict__ x,        // [B,129,250]
    const unsigned short* __restrict__ ahi,
    const unsigned short* __restrict__ alo,
    const float* __restrict__ bias2,
    const float* __restrict__ w128,
    const float* __restrict__ conv_w,
    const float* __restrict__ conv_b,
    const float* __restrict__ dt_bias,
    const float* __restrict__ A_log,
    const float* __restrict__ Dv,
    const float* __restrict__ norm_w,
    const float* __restrict__ vv,
    const float* __restrict__ head_b,
    float* __restrict__ out)
{
    __shared__ unsigned short xh[2][NKS * 64 * 8];   // bf16-hi x, frag order (16 KB)
    __shared__ unsigned short xl[2][NKS * 64 * 8];   // bf16-lo (16 KB)
    __shared__ unsigned short zxlo[2][512 * ZRS];    // bf16 zx rows 0..511 (68 KB)
    __shared__ float zxf[2][36 * ZRF];               // fp32 zx rows 512..547 (9.3 KB)
    __shared__ float x128b[16][2][TC];               // c=128 raw per chunk (2 KB)
    __shared__ float bcw[4][TC][40];                 // per-compute-wave B|C|dt|dA (10 KB)
    __shared__ float smp[2][2][TC][8];               // [par][mb][tt][2wq(+1)] (2 KB)

    const int b2   = blockIdx.x;
    const int tid  = threadIdx.x;
    const int lane = tid & 63;
    const int wv   = tid >> 6;            // 0..7
    const bool isC = (wv < 4);
    const int wq   = wv & 3;
    const int p    = (wq << 6) | lane;    // compute channel
    const int atid = tid & 255;           // mfma-group linear id

    // ---- compute-wave params ----
    float bz = 0.f, bx = 0.f, w1z = 0.f, w1x = 0.f;
    float cw0 = 0.f, cw1 = 0.f, cw2 = 0.f, cw3 = 0.f, ccb = 0.f;
    float Dh = 0.f, nv = 0.f;
    float bxb = 0.f, w1b = 0.f, e0 = 0.f, e1 = 0.f, e2 = 0.f, e3 = 0.f, eb = 0.f;
    float dtb = 0.f, Ah = 0.f;
    if (isC) {
        bz = bias2[p];          w1z = w128[p];
        bx = bias2[DINNER + p]; w1x = w128[DINNER + p];
        cw0 = conv_w[p * 4 + 0]; cw1 = conv_w[p * 4 + 1];
        cw2 = conv_w[p * 4 + 2]; cw3 = conv_w[p * 4 + 3];
        ccb = conv_b[p];
        Dh = Dv[wq];
        nv = norm_w[p] * vv[p];
        if (lane < 36) {
            bxb = bias2[512 + lane]; w1b = w128[512 + lane];
            if (lane < 32) {
                int ch = DINNER + lane;
                e0 = conv_w[ch * 4 + 0]; e1 = conv_w[ch * 4 + 1];
                e2 = conv_w[ch * 4 + 2]; e3 = conv_w[ch * 4 + 3];
                eb = conv_b[ch];
            } else {
                dtb = dt_bias[lane - 32];
                Ah  = -expf(A_log[lane - 32]);
            }
        }
    }

    float hs0[DSTATE], hs1[DSTATE], xa[TC], za[TC];
    float c1_[2] = {0.f, 0.f}, c2_[2] = {0.f, 0.f}, c3_[2] = {0.f, 0.f};
    float g1_[2] = {0.f, 0.f}, g2_[2] = {0.f, 0.f}, g3_[2] = {0.f, 0.f};
    float outacc = 0.f;
#pragma unroll
    for (int n = 0; n < DSTATE; ++n) { hs0[n] = 0.f; hs1[n] = 0.f; }

    const float* xbase = x + (size_t)2 * b2 * NCH * NT;

    // ---- mfma-wave: stage x chunk into xh/xl (frag order) + x128b ----
    auto stage_x = [&](auto Lc, int cidx) {
        constexpr int L  = decltype(Lc)::value;
        constexpr int HP = L / 2;
        constexpr int NP2 = 2 * NCH * HP;
        const int par = cidx & 1;
        const int t0 = cidx * TC;
        float2 pr[9];
#pragma unroll
        for (int k = 0; k * 256 < NP2; ++k) {
            int u = atid + 256 * k;
            if (u < NP2) {
                int mbx = (u >= NCH * HP) ? 1 : 0;
                int rem = u - mbx * NCH * HP;
                int c = rem / HP, tp = rem - c * HP;
                pr[k] = *(const float2*)(xbase + (size_t)mbx * NCH * NT + c * NT + t0 + 2 * tp);
            }
        }
#pragma unroll
        for (int k = 0; k * 256 < NP2; ++k) {
            int u = atid + 256 * k;
            if (u < NP2) {
                int mbx = (u >= NCH * HP) ? 1 : 0;
                int rem = u - mbx * NCH * HP;
                int c = rem / HP, tp = rem - c * HP;
                float2 v = pr[k];
                if (c < 128) {
                    int ks = c >> 4, half = (c >> 3) & 1, i = c & 7;
                    int col = mbx * 16 + 2 * tp;
                    int pos = (ks * 64 + half * 32 + col) * 8 + i;
                    unsigned short h0 = f2bf(v.x), h1 = f2bf(v.y);
                    xh[par][pos]     = h0;
                    xh[par][pos + 8] = h1;
                    xl[par][pos]     = f2bf(v.x - bf2f(h0));
                    xl[par][pos + 8] = f2bf(v.y - bf2f(h1));
                } else {
                    x128b[cidx][mbx][2 * tp]     = v.x;
                    x128b[cidx][mbx][2 * tp + 1] = v.y;
                }
            }
        }
    };

    // ---- mfma-wave: GEMM chunk cidx into zx[cidx&1] ----
    auto gemm = [&](int cidx) {
        const int par = cidx & 1;
        short8 bh[NKS], bl[NKS];
#pragma unroll
        for (int ks = 0; ks < NKS; ++ks) {
            bh[ks] = *(const short8*)&xh[par][(ks * 64 + lane) * 8];
            bl[ks] = *(const short8*)&xl[par][(ks * 64 + lane) * 8];
        }
        for (int mt = wq; mt < NMT; mt += 4) {
            f32x16 a0 = {0.f,0.f,0.f,0.f,0.f,0.f,0.f,0.f,0.f,0.f,0.f,0.f,0.f,0.f,0.f,0.f};
            f32x16 a1 = {0.f,0.f,0.f,0.f,0.f,0.f,0.f,0.f,0.f,0.f,0.f,0.f,0.f,0.f,0.f,0.f};
#pragma unroll
            for (int ks = 0; ks < NKS; ++ks) {
                size_t fo = (((size_t)(mt * NKS + ks)) * 64 + lane) * 8;
                short8 ah = *(const short8*)(ahi + fo);
                short8 al = *(const short8*)(alo + fo);
                a0 = __builtin_amdgcn_mfma_f32_32x32x16_bf16(ah, bh[ks], a0, 0, 0, 0);
                a1 = __builtin_amdgcn_mfma_f32_32x32x16_bf16(ah, bl[ks], a1, 0, 0, 0);
                a1 = __builtin_amdgcn_mfma_f32_32x32x16_bf16(al, bh[ks], a1, 0, 0, 0);
            }
            int col = lane & 31;
#pragma unroll
            for (int r = 0; r < 16; ++r) {
                int j = mt * 32 + (r & 3) + 8 * (r >> 2) + 4 * (lane >> 5);
                float v = a0[r] + a1[r];
                if (j < 512)            zxlo[par][j * ZRS + col] = f2bf(v);
                else if (j < DPROJ)     zxf[par][(j - 512) * ZRF + col] = v;
            }
        }
    };

    // ---- compute-wave: one stage ----
    auto cstage = [&](auto CLc, int s) {
        constexpr int CL = decltype(CLc)::value;
        const int par = s & 1;
        if (s > 0 && wq < 2 && lane < TC) {       // fold prev chunk
            const float* sp = smp[(s - 1) & 1][wq][lane];
            float s1 = sp[0] + sp[2] + sp[4] + sp[6];
            float s2 = sp[1] + sp[3] + sp[5] + sp[7];
            outacc = fmaf(s2, rsqrtf(fmaf(s1, 1.f / DINNER, 1e-5f)), outacc);
        }
#pragma unroll
        for (int mb = 0; mb < 2; ++mb) {
            float* hsp = mb ? hs1 : hs0;
            // --- BC/dt (redundant per wave, lanes<36) ---
            if (lane < 36) {
                if (lane < 32) {
                    float r1 = g1_[mb], r2 = g2_[mb], r3 = g3_[mb];
#pragma unroll
                    for (int tt = 0; tt < CL; ++tt) {
                        float xm = x128b[s][mb][tt];
                        float raw = zxf[par][lane * ZRF + mb * 16 + tt] + bxb + w1b * xm;
                        float cv = fmaf(e3, raw, fmaf(e2, r1, fmaf(e1, r2, fmaf(e0, r3, eb))));
                        r3 = r2; r2 = r1; r1 = raw;
                        bcw[wq][tt][lane] = silu_f(cv);
                    }
                    g1_[mb] = r1; g2_[mb] = r2; g3_[mb] = r3;
                } else {
                    int h = lane - 32;
#pragma unroll
                    for (int tt = 0; tt < CL; ++tt) {
                        float xm = x128b[s][mb][tt];
                        float val = zxf[par][lane * ZRF + mb * 16 + tt] + bxb + w1b * xm + dtb;
                        float dt = (val > 20.f) ? val : log1pf(expf(val));
                        bcw[wq][tt][32 + h] = dt;
                        bcw[wq][tt][36 + h] = __expf(dt * Ah);
                    }
                }
            }
            __builtin_amdgcn_wave_barrier();   // keep ds_write before ds_read (same wave, in-order LDS)
            // --- own conv + silu ---
            {
                float r1 = c1_[mb], r2 = c2_[mb], r3 = c3_[mb];
#pragma unroll
                for (int tt = 0; tt < CL; ++tt) {
                    float xm = x128b[s][mb][tt];
                    int col = mb * 16 + tt;
                    float zraw = bf2f(zxlo[par][p * ZRS + col]) + bz + w1z * xm;
                    float xraw = bf2f(zxlo[par][(256 + p) * ZRS + col]) + bx + w1x * xm;
                    float cv = fmaf(cw3, xraw, fmaf(cw2, r1, fmaf(cw1, r2, fmaf(cw0, r3, ccb))));
                    r3 = r2; r2 = r1; r1 = xraw;
                    xa[tt] = silu_f(cv);
                    za[tt] = silu_f(zraw);
                }
                c1_[mb] = r1; c2_[mb] = r2; c3_[mb] = r3;
            }
            // --- scan + reductions ---
#pragma unroll
            for (int tt = 0; tt < CL; ++tt) {
                float xv  = xa[tt];
                float g   = za[tt];
                float dtv = bcw[wq][tt][32 + wq];
                float dAv = bcw[wq][tt][36 + wq];
                float bcv = bcw[wq][tt][lane & 31];
                float dx = dtv * xv;
                float y0 = 0.f, y1 = 0.f, y2 = 0.f, y3 = 0.f;
#pragma unroll
                for (int n = 0; n < 4; ++n) {
                    float b0 = rdlane(bcv, n),      cc0 = rdlane(bcv, DSTATE + n);
                    float b1 = rdlane(bcv, 4 + n),  cc1 = rdlane(bcv, DSTATE + 4 + n);
                    float b2v = rdlane(bcv, 8 + n), cc2 = rdlane(bcv, DSTATE + 8 + n);
                    float b3 = rdlane(bcv, 12 + n), cc3 = rdlane(bcv, DSTATE + 12 + n);
                    hsp[n]      = fmaf(hsp[n],      dAv, dx * b0);  y0 = fmaf(hsp[n],      cc0, y0);
                    hsp[4 + n]  = fmaf(hsp[4 + n],  dAv, dx * b1);  y1 = fmaf(hsp[4 + n],  cc1, y1);
                    hsp[8 + n]  = fmaf(hsp[8 + n],  dAv, dx * b2v); y2 = fmaf(hsp[8 + n],  cc2, y2);
                    hsp[12 + n] = fmaf(hsp[12 + n], dAv, dx * b3);  y3 = fmaf(hsp[12 + n], cc3, y3);
                }
                float val = fmaf(Dh, xv, (y0 + y1) + (y2 + y3)) * g;
                float s1 = wave_sum63(val * val);
                float s2 = wave_sum63(val * nv);
                if (lane == 63) {
                    smp[par][mb][tt][2 * wq]     = s1;
                    smp[par][mb][tt][2 * wq + 1] = s2;
                }
            }
        }
    };

    // ---- prologue ----
    if (!isC) stage_x(IC<16>{}, 0);
    __syncthreads();
    if (!isC) { gemm(0); stage_x(IC<16>{}, 1); }
    __syncthreads();

    // ---- main stages ----
    for (int s = 0; s <= 12; ++s) {
        if (isC) cstage(IC<16>{}, s);
        else     { gemm(s + 1); stage_x(IC<16>{}, s + 2); }
        __syncthreads();
    }
    if (isC) cstage(IC<16>{}, 13); else { gemm(14); stage_x(IC<10>{}, 15); }
    __syncthreads();
    if (isC) cstage(IC<16>{}, 14); else gemm(15);
    __syncthreads();
    if (isC) cstage(IC<10>{}, 15);
    __syncthreads();

    // ---- epilogue ----
    if (isC && wq < 2) {
        if (lane < 10) {   // fold chunk 15 (par 1, CL=10)
            const float* sp = smp[1][wq][lane];
            float s1 = sp[0] + sp[2] + sp[4] + sp[6];
            float s2 = sp[1] + sp[3] + sp[5] + sp[7];
            outacc = fmaf(s2, rsqrtf(fmaf(s1, 1.f / DINNER, 1e-5f)), outacc);
        }
        float tot = wave_sum63(outacc);
        if (lane == 63) out[2 * b2 + wq] = head_b[0] + tot * (1.f / NT);
    }
}

extern "C" void kernel_launch(void* const* d_in, const int* in_sizes, int n_in,
                              void* d_out, int out_size, void* d_ws, size_t ws_size,
                              hipStream_t stream) {
    const float* x         = (const float*)d_in[0];
    const float* mixer_w   = (const float*)d_in[1];
    const float* mixer_b   = (const float*)d_in[2];
    const float* in_proj_w = (const float*)d_in[3];
    const float* conv_w    = (const float*)d_in[4];
    const float* conv_b    = (const float*)d_in[5];
    const float* dt_bias   = (const float*)d_in[6];
    const float* A_log     = (const float*)d_in[7];
    const float* Dp        = (const float*)d_in[8];
    const float* norm_w    = (const float*)d_in[9];
    const float* out_proj_w= (const float*)d_in[10];
    const float* head_w    = (const float*)d_in[11];
    const float* head_b    = (const float*)d_in[12];
    float* out = (float*)d_out;

    int B = in_sizes[0] / (NCH * NT);   // 512

    const size_t FRAG = (size_t)NMT * NKS * 64 * 8;   // shorts per matrix
    unsigned short* ahi = (unsigned short*)d_ws;
    unsigned short* alo = ahi + FRAG;
    float* bias2 = (float*)(alo + FRAG);
    float* w128  = bias2 + DPROJ;
    float* vvp   = w128 + DPROJ;

    k_prep<<<NMT * NKS + 2, 256, 0, stream>>>(in_proj_w, mixer_w, mixer_b,
                                              head_w, out_proj_w,
                                              ahi, alo, bias2, w128, vvp);
    k_fused<<<B / 2, 512, 0, stream>>>(x, ahi, alo, bias2, w128, conv_w, conv_b,
                                       dt_bias, A_log, Dp, norm_w, vvp, head_b, out);
}